// Round 1
// 470.244 us; speedup vs baseline: 1.0113x; 1.0113x over previous
//
#include <hip/hip_runtime.h>

// V: (1, 80, 96, 112, 16) f32  ->  out: (1, 160, 192, 224, 16) f32
// Separable 2x linear upsample, edge clamp. even = copy, odd = avg(i, i+1).
//
// Block = one input (d0,h0) site -> output row-quad {2d0,2d0+1} x {2h0,2h0+1}.
// 896 threads; thread t owns output float4 column t of each of the 4 rows, so
// every store instruction is perfectly contiguous (1024 B / wave).
// Reference grouping preserved exactly:
//   out(2d,2h)     = A
//   out(2d,2h+1)   = 0.5(A+B)
//   out(2d+1,2h)   = 0.5(A+C)
//   out(2d+1,2h+1) = 0.5(0.5(A+C) + 0.5(B+D))
// then w-odd applies 0.5(y[w] + y[w+1]) last. avg(x,x)==x exactly, so even
// lanes use a duplicated second index instead of a branch.
//
// R1 change: output rows are stored NON-TEMPORALLY (nt flag). The 440 MB
// output stream is never re-read; letting it allocate in L2 thrashes the
// 32 MB aggregate L2 and evicts the input rows that the 4-way inter-block
// reuse (A/B/C/D) depends on. nt stores keep the input resident in L2.

#define DV 80
#define HV 96
#define WV 112
#define ROW4 (WV * 4)          // 448 float4 per input row
#define OROW4 (2 * WV * 4)     // 896 float4 per output row

typedef float v4f __attribute__((ext_vector_type(4)));

__device__ __forceinline__ float4 avg4(float4 x, float4 y) {
    return make_float4(0.5f * (x.x + y.x), 0.5f * (x.y + y.y),
                       0.5f * (x.z + y.z), 0.5f * (x.w + y.w));
}

__device__ __forceinline__ void store_nt(float4* p, float4 v) {
    __builtin_nontemporal_store(*reinterpret_cast<const v4f*>(&v),
                                reinterpret_cast<v4f*>(p));
}

__global__ __launch_bounds__(896) void UpsampleInterp_kernel(
        const float4* __restrict__ in, float4* __restrict__ out) {
    const int h0 = blockIdx.x;             // 0..95
    const int d0 = blockIdx.y;             // 0..79
    const int t  = threadIdx.x;            // 0..895
    const int c4 = t & 3;                  // channel quad
    const int wo = t >> 2;                 // 0..223
    const int wi = wo >> 1;                // 0..111
    const int wodd = wo & 1;
    const int wib = (wi + 1 < WV) ? wi + 1 : WV - 1;
    const int i1 = wodd ? wib : wi;        // duplicate for even lanes

    const int d1 = (d0 + 1 < DV) ? d0 + 1 : DV - 1;  // block-uniform
    const int h1 = (h0 + 1 < HV) ? h0 + 1 : HV - 1;  // block-uniform

    const int baseA = (d0 * HV + h0) * ROW4 + c4;
    const int baseB = (d0 * HV + h1) * ROW4 + c4;
    const int baseC = (d1 * HV + h0) * ROW4 + c4;
    const int baseD = (d1 * HV + h1) * ROW4 + c4;

    // 8 independent loads (L1 serves the 2-lane duplicates)
    const float4 A0 = in[baseA + 4 * wi], A1 = in[baseA + 4 * i1];
    const float4 B0 = in[baseB + 4 * wi], B1 = in[baseB + 4 * i1];
    const float4 C0 = in[baseC + 4 * wi], C1 = in[baseC + 4 * i1];
    const float4 D0 = in[baseD + 4 * wi], D1 = in[baseD + 4 * i1];

    const float4 ab0 = avg4(A0, B0), ab1 = avg4(A1, B1);
    const float4 ac0 = avg4(A0, C0), ac1 = avg4(A1, C1);
    const float4 bd0 = avg4(B0, D0), bd1 = avg4(B1, D1);

    const float4 r00 = avg4(A0, A1);
    const float4 r01 = avg4(ab0, ab1);
    const float4 r10 = avg4(ac0, ac1);
    const float4 r11 = avg4(avg4(ac0, bd0), avg4(ac1, bd1));

    // 4 contiguous row stores — non-temporal (output is write-once)
    const int ob = ((2 * d0) * (2 * HV) + (2 * h0)) * OROW4 + t;
    store_nt(&out[ob],                            r00);   // (2d0,   2h0)
    store_nt(&out[ob + OROW4],                    r01);   // (2d0,   2h0+1)
    store_nt(&out[ob + (2 * HV) * OROW4],         r10);   // (2d0+1, 2h0)
    store_nt(&out[ob + (2 * HV) * OROW4 + OROW4], r11);   // (2d0+1, 2h0+1)
}

extern "C" void kernel_launch(void* const* d_in, const int* in_sizes, int n_in,
                              void* d_out, int out_size, void* d_ws, size_t ws_size,
                              hipStream_t stream) {
    const float4* in = (const float4*)d_in[0];
    float4* out = (float4*)d_out;
    dim3 grid(HV, DV);  // (h0, d0) = (96, 80)
    UpsampleInterp_kernel<<<grid, 896, 0, stream>>>(in, out);
}